// Round 1
// baseline (412.711 us; speedup 1.0000x reference)
//
#include <hip/hip_runtime.h>
#include <hip/hip_bf16.h>
#include <cstddef>

typedef __attribute__((ext_vector_type(8))) short short8;   // 8 bf16 = 4 VGPR
typedef __attribute__((ext_vector_type(4))) float f32x4;

#define LSTR 40   // LDS row stride in bf16 elements (80 B) -- generic sk_body only

static __device__ __forceinline__ short8 pack8(float4 f0, float4 f1) {
    union { __hip_bfloat162 h[4]; short8 s; } u;
    u.h[0] = __float22bfloat162_rn(make_float2(f0.x, f0.y));
    u.h[1] = __float22bfloat162_rn(make_float2(f0.z, f0.w));
    u.h[2] = __float22bfloat162_rn(make_float2(f1.x, f1.y));
    u.h[3] = __float22bfloat162_rn(make_float2(f1.z, f1.w));
    return u.s;
}

// ===========================================================================
// Generic split-K bf16 MFMA body: adds A[m0:m0+128, kbeg:kend] @ W^T tile
// into C via atomicAdd. Tile 128(M) x 64(N), BK=32, 256 thr (4 waves, each
// 32 rows x 64 cols). N bounds-checked. C must be zero-initialized.
// ===========================================================================
static __device__ __forceinline__ void sk_body(
    const float* __restrict__ A, int lda,
    const float* __restrict__ W,
    const float* __restrict__ bias, int addbias,
    float* __restrict__ C, int ldc, int N,
    int kbeg, int kend, int n0, int m0)
{
    __shared__ short As[128 * LSTR];
    __shared__ short Ws[64 * LSTR];
    const int tid  = threadIdx.x;
    const int lane = tid & 63;
    const int wave = tid >> 6;
    const int wm = wave * 32;

    f32x4 acc[2][4];
    #pragma unroll
    for (int i = 0; i < 2; ++i)
        #pragma unroll
        for (int j = 0; j < 4; ++j)
            acc[i][j] = (f32x4){0.f, 0.f, 0.f, 0.f};

    const int srow  = tid >> 2;          // 0..63
    const int skoff = (tid & 3) * 8;
    const int frow  = lane & 15;
    const int fkoff = (lane >> 4) * 8;

    for (int k0 = kbeg; k0 < kend; k0 += 32) {
        #pragma unroll
        for (int p = 0; p < 2; ++p) {
            int row = srow + p * 64;
            const float* sa = A + (size_t)(m0 + row) * lda + k0 + skoff;
            *(short8*)(As + row * LSTR + skoff) =
                pack8(*(const float4*)sa, *(const float4*)(sa + 4));
        }
        {
            int n = n0 + srow;
            short8 v = (short8){0,0,0,0,0,0,0,0};
            if (n < N) {
                const float* sw = W + (size_t)n * lda + k0 + skoff;
                v = pack8(*(const float4*)sw, *(const float4*)(sw + 4));
            }
            *(short8*)(Ws + srow * LSTR + skoff) = v;
        }
        __syncthreads();

        short8 af[2], bf[4];
        #pragma unroll
        for (int i = 0; i < 2; ++i)
            af[i] = *(const short8*)(As + (wm + i * 16 + frow) * LSTR + fkoff);
        #pragma unroll
        for (int j = 0; j < 4; ++j)
            bf[j] = *(const short8*)(Ws + (j * 16 + frow) * LSTR + fkoff);
        #pragma unroll
        for (int i = 0; i < 2; ++i)
            #pragma unroll
            for (int j = 0; j < 4; ++j)
                acc[i][j] = __builtin_amdgcn_mfma_f32_16x16x32_bf16(af[i], bf[j], acc[i][j], 0, 0, 0);
        __syncthreads();
    }

    const int cl = lane & 15;
    const int rq = (lane >> 4) * 4;
    #pragma unroll
    for (int j = 0; j < 4; ++j) {
        int gc = n0 + j * 16 + cl;
        if (gc >= N) continue;
        float b = addbias ? bias[gc] : 0.f;
        #pragma unroll
        for (int i = 0; i < 2; ++i) {
            int gr = m0 + wm + i * 16 + rq;
            #pragma unroll
            for (int r = 0; r < 4; ++r)
                atomicAdd(C + (size_t)(gr + r) * ldc + gc, acc[i][j][r] + b);
        }
    }
}

// generic wrapper: grid (ceil(N/64), ksplit, M/128)
__global__ __launch_bounds__(256) void gemm_sk(
    const float* __restrict__ A, const float* __restrict__ W,
    const float* __restrict__ bias, float* __restrict__ C,
    int N, int K, int kchunk, int ldc)
{
    int kbeg = blockIdx.y * kchunk;
    sk_body(A, K, W, bias, bias != nullptr && blockIdx.y == 0,
            C, ldc, N, kbeg, kbeg + kchunk, blockIdx.x * 64, blockIdx.z * 128);
}

// three h0 projections fused: weight/output selected by n-tile. grid (24,8)
__global__ __launch_bounds__(256) void hproj3_mfma(
    const float* __restrict__ h0,
    const float* __restrict__ Wa, const float* __restrict__ Wb, const float* __restrict__ Wc,
    float* __restrict__ hbase)
{
    int n0g = blockIdx.x * 64;
    int wsel = n0g >> 9;
    const float* W = (wsel == 0) ? Wa : (wsel == 1) ? Wb : Wc;
    float* C = hbase + (size_t)wsel * 128 * 512;
    int kbeg = blockIdx.y * 128;
    sk_body(h0, 1024, W, nullptr, 0, C, 512, 512, kbeg, kbeg + 128, n0g & 511, 0);
}

// both context projections fused into ctx[B,2,C]. grid (8,8,2)
__global__ __launch_bounds__(256) void ctxproj_mfma(
    const float* __restrict__ attv, const float* __restrict__ Wv,
    const float* __restrict__ atta, const float* __restrict__ Wa,
    float* __restrict__ ctx)
{
    const float* A; const float* W; float* C; int lda, kb, ke;
    if (blockIdx.z == 0) { A = attv; W = Wv; C = ctx;       lda = 1024; kb = blockIdx.y * 128; ke = kb + 128; }
    else                 { A = atta; W = Wa; C = ctx + 512; lda = 512;  kb = blockIdx.y * 64;  ke = kb + 64;  }
    sk_body(A, lda, W, nullptr, 0, C, 1024, 512, kb, ke, blockIdx.x * 64, 0);
}

// both LSTM gate GEMMs fused (biases applied in lstm_kernel). grid (64,8)
__global__ __launch_bounds__(256) void gates_mfma(
    const float* __restrict__ xb, const float* __restrict__ W_ih,
    const float* __restrict__ h0, const float* __restrict__ W_hh,
    float* __restrict__ gates)
{
    int pair = blockIdx.y >> 2;
    const float* A = pair ? h0 : xb;
    const float* W = pair ? W_hh : W_ih;
    int kb = (blockIdx.y & 3) * 256;
    sk_body(A, 1024, W, nullptr, 0, gates, 4096, 4096, kb, kb + 256, blockIdx.x * 64, 0);
}

// ===========================================================================
// Fused encoder-projection + attention-score kernel, BOTH modalities in one
// launch. NEW structure this round:
//   Tile 128(M) x 128(N), BK=32, 256 thr (4 waves 2x2: each 64m x 64n,
//   16 MFMA/wave/K-step -- 2x the MFMA-per-staged-byte of the old 64x128).
//   LDS: linear [row][32] bf16 with XOR-swizzled 16B k-slot
//   (phys = logical ^ ((row>>1)&3)) -> ~2-way banks on both ds_write_b128
//   and ds_read_b128 (2-way is free), vs the old 4-8-way (6.3M conflicts).
//   Explicit next-K-tile register prefetch issued between the barriers so
//   HBM latency overlaps the ds_read+MFMA phase (T14 async-stage split).
// Epilogue unchanged: p = sum_cols tanh(v1+v2)*W3 reduced over 16 col-lanes,
// atomicAdd into sc[row]. N=512 exactly (4 n-tiles, no bounds checks).
// Block order: m-minor, m-tiles per modality % 8 == 0 -> all 4 n-users of
// an A-tile land on the same XCD (blockIdx%8 round-robin) -> A read ~once.
// grid: 256 visual blocks (n*64+m) then 512 audio blocks (256 + n*128+m).
// ===========================================================================
__global__ __launch_bounds__(256) void scores_fused(
    const float* __restrict__ encv, const float* __restrict__ W_va2,
    const float* __restrict__ hv1,  const float* __restrict__ W_va3,
    float* __restrict__ scv,
    const float* __restrict__ enca, const float* __restrict__ W_aa2,
    const float* __restrict__ ha1,  const float* __restrict__ W_aa3,
    float* __restrict__ sca)
{
    __shared__ short As[128 * 32];
    __shared__ short Ws[128 * 32];

    const float *A, *W, *v1, *W3;
    float* sc;
    int K, tshift, n0, m0;
    int idx = blockIdx.x;
    if (idx < 256) {            // visual: M=8192, K=1024, T=64 -> 64 mtiles
        n0 = (idx >> 6) * 128;  m0 = (idx & 63) * 128;
        A = encv; W = W_va2; v1 = hv1; W3 = W_va3; sc = scv;
        K = 1024; tshift = 6;
    } else {                    // audio: M=16384, K=512, T=128 -> 128 mtiles
        idx -= 256;
        n0 = (idx >> 7) * 128;  m0 = (idx & 127) * 128;
        A = enca; W = W_aa2; v1 = ha1; W3 = W_aa3; sc = sca;
        K = 512; tshift = 7;
    }

    const int tid  = threadIdx.x;
    const int lane = tid & 63;
    const int wave = tid >> 6;
    const int wm = (wave >> 1) * 64;
    const int wn = (wave & 1) * 64;

    f32x4 acc[4][4];
    #pragma unroll
    for (int i = 0; i < 4; ++i)
        #pragma unroll
        for (int j = 0; j < 4; ++j)
            acc[i][j] = (f32x4){0.f, 0.f, 0.f, 0.f};

    // --- staging: thread -> (row = tid>>1, k-half = tid&1), 16 floats each ---
    const int srow = tid >> 1;           // 0..127
    const int skh  = tid & 1;            // 0..1 (16-float half of the 32-k tile)
    const float* ga = A + (size_t)(m0 + srow) * K + skh * 16;
    const float* gw = W + (size_t)(n0 + srow) * K + skh * 16;
    // XOR swizzle: physical 16B slot = logical ^ ((row>>1)&3)
    const int fs = (srow >> 1) & 3;
    short* wa0 = As + srow * 32 + (((skh * 2)     ^ fs) * 8);
    short* wa1 = As + srow * 32 + (((skh * 2 + 1) ^ fs) * 8);
    short* ww0 = Ws + srow * 32 + (((skh * 2)     ^ fs) * 8);
    short* ww1 = Ws + srow * 32 + (((skh * 2 + 1) ^ fs) * 8);

    // --- fragment read addresses (wm/wn multiples of 16 -> f depends on frow only)
    const int frow  = lane & 15;
    const int hi    = lane >> 4;
    const int fslot = (hi ^ ((frow >> 1) & 3)) * 8;
    const short* ra = As + (wm + frow) * 32 + fslot;   // + i*512 per 16-row step
    const short* rb = Ws + (wn + frow) * 32 + fslot;

    // prologue: load K-tile 0 into registers
    float4 pa[4], pw[4];
    #pragma unroll
    for (int q = 0; q < 4; ++q) {
        pa[q] = *(const float4*)(ga + q * 4);
        pw[q] = *(const float4*)(gw + q * 4);
    }

    for (int k0 = 0; k0 < K; k0 += 32) {
        // convert + stage current tile
        *(short8*)wa0 = pack8(pa[0], pa[1]);
        *(short8*)wa1 = pack8(pa[2], pa[3]);
        *(short8*)ww0 = pack8(pw[0], pw[1]);
        *(short8*)ww1 = pack8(pw[2], pw[3]);
        __syncthreads();

        // issue next-tile global loads now; they complete under ds_read+MFMA
        if (k0 + 32 < K) {
            #pragma unroll
            for (int q = 0; q < 4; ++q) {
                pa[q] = *(const float4*)(ga + k0 + 32 + q * 4);
                pw[q] = *(const float4*)(gw + k0 + 32 + q * 4);
            }
        }

        short8 af[4], bf[4];
        #pragma unroll
        for (int i = 0; i < 4; ++i)
            af[i] = *(const short8*)(ra + i * 512);
        #pragma unroll
        for (int j = 0; j < 4; ++j)
            bf[j] = *(const short8*)(rb + j * 512);
        #pragma unroll
        for (int i = 0; i < 4; ++i)
            #pragma unroll
            for (int j = 0; j < 4; ++j)
                acc[i][j] = __builtin_amdgcn_mfma_f32_16x16x32_bf16(af[i], bf[j], acc[i][j], 0, 0, 0);
        __syncthreads();
    }

    // epilogue: p = sum_cols tanh(v1[b,c] + v2) * W3[c]; reduce 16 col-lanes
    const int cl = lane & 15;
    const int rq = hi * 4;
    #pragma unroll
    for (int i = 0; i < 4; ++i) {
        #pragma unroll
        for (int r = 0; r < 4; ++r) {
            int gr = m0 + wm + i * 16 + rq + r;
            const float* v1row = v1 + (size_t)(gr >> tshift) * 512;
            float p = 0.f;
            #pragma unroll
            for (int j = 0; j < 4; ++j) {
                int gc = n0 + wn + j * 16 + cl;
                p += tanhf(v1row[gc] + acc[i][j][r]) * W3[gc];
            }
            p += __shfl_xor(p, 1, 64);
            p += __shfl_xor(p, 2, 64);
            p += __shfl_xor(p, 4, 64);
            p += __shfl_xor(p, 8, 64);
            if (cl == 0) atomicAdd(sc + gr, p);
        }
    }
}

// ===========================================================================
// Softmax over T + weighted sum, both modalities in one launch.
// grid (B, 6): y<4 -> visual e-chunk y; y>=4 -> audio e-chunk y-4.
// ===========================================================================
__global__ __launch_bounds__(256) void attend_out2(
    const float* __restrict__ scv, const float* __restrict__ encv, float* __restrict__ attv,
    const float* __restrict__ sca, const float* __restrict__ enca, float* __restrict__ atta)
{
    const float* sc; const float* enc; float* out;
    int T, E, ec;
    if (blockIdx.y < 4) { sc = scv; enc = encv; out = attv; T = 64;  E = 1024; ec = blockIdx.y; }
    else                { sc = sca; enc = enca; out = atta; T = 128; E = 512;  ec = blockIdx.y - 4; }

    __shared__ float ew[128];
    const int b = blockIdx.x, tid = threadIdx.x;
    __shared__ float raw[128];
    if (tid < T) raw[tid] = sc[(size_t)b * T + tid];
    __syncthreads();
    float m = -1e30f;
    for (int t = 0; t < T; ++t) m = fmaxf(m, raw[t]);
    if (tid < T) ew[tid] = __expf(raw[tid] - m);
    __syncthreads();
    float sum = 0.f;
    for (int t = 0; t < T; ++t) sum += ew[t];
    const float inv = 1.f / sum;

    const int e = ec * 256 + tid;
    const float* encb = enc + (size_t)b * T * E + e;
    float acc = 0.f;
    for (int t = 0; t < T; ++t)
        acc += ew[t] * encb[(size_t)t * E];
    out[(size_t)b * E + e] = acc * inv;
}

// ===========================================================================
// Cross-modal attention + build x = [input | tanh(final_ctx)]
// ===========================================================================
__global__ __launch_bounds__(256) void cross_kernel(
    const float* __restrict__ hc1, const float* __restrict__ v2c,
    const float* __restrict__ W3, const float* __restrict__ ctx,
    const float* __restrict__ inp, float* __restrict__ x)
{
    const int C = 512;
    __shared__ float red[256];
    __shared__ float aw[2];
    const int b = blockIdx.x, tid = threadIdx.x;

    float p0 = 0.f, p1 = 0.f;
    for (int c = tid; c < C; c += 256) {
        float h = hc1[(size_t)b * C + c], w = W3[c];
        p0 += tanhf(h + v2c[(size_t)(b * 2 + 0) * C + c]) * w;
        p1 += tanhf(h + v2c[(size_t)(b * 2 + 1) * C + c]) * w;
    }
    red[tid] = p0; __syncthreads();
    for (int s = 128; s; s >>= 1) { if (tid < s) red[tid] += red[tid + s]; __syncthreads(); }
    float s0 = red[0];
    __syncthreads();
    red[tid] = p1; __syncthreads();
    for (int s = 128; s; s >>= 1) { if (tid < s) red[tid] += red[tid + s]; __syncthreads(); }
    if (tid == 0) {
        float s1 = red[0];
        float m = fmaxf(s0, s1);
        float e0 = __expf(s0 - m), e1 = __expf(s1 - m);
        float inv = 1.f / (e0 + e1);
        aw[0] = e0 * inv; aw[1] = e1 * inv;
    }
    __syncthreads();
    float a0 = aw[0], a1 = aw[1];
    for (int c = tid; c < C; c += 256) {
        float fc = a0 * ctx[(size_t)(b * 2 + 0) * C + c]
                 + a1 * ctx[(size_t)(b * 2 + 1) * C + c];
        x[(size_t)b * 1024 + 512 + c] = tanhf(fc);
        x[(size_t)b * 1024 + c] = inp[(size_t)b * 512 + c];
    }
}

// ===========================================================================
// LSTM pointwise (biases folded in here)
// ===========================================================================
__global__ __launch_bounds__(256) void lstm_kernel(
    const float* __restrict__ gates, const float* __restrict__ c0,
    const float* __restrict__ b_ih, const float* __restrict__ b_hh,
    float* __restrict__ hout, float* __restrict__ cout)
{
    const int idx = blockIdx.x * 256 + threadIdx.x;   // B*H = 131072
    const int b = idx >> 10, h = idx & 1023;
    const float* g = gates + (size_t)b * 4096;
    float gi = g[h]        + b_ih[h]        + b_hh[h];
    float gf = g[1024 + h] + b_ih[1024 + h] + b_hh[1024 + h];
    float gg = g[2048 + h] + b_ih[2048 + h] + b_hh[2048 + h];
    float go = g[3072 + h] + b_ih[3072 + h] + b_hh[3072 + h];
    float si = 1.f / (1.f + __expf(-gi));
    float sf = 1.f / (1.f + __expf(-gf));
    float so = 1.f / (1.f + __expf(-go));
    float cn = sf * c0[idx] + si * tanhf(gg);
    float hn = so * tanhf(cn);
    cout[idx] = cn;
    hout[idx] = hn;
}

// ---------------------------------------------------------------------------
extern "C" void kernel_launch(void* const* d_in, const int* in_sizes, int n_in,
                              void* d_out, int out_size, void* d_ws, size_t ws_size,
                              hipStream_t stream)
{
    const float* inp    = (const float*)d_in[0];
    const float* encv   = (const float*)d_in[1];
    const float* enca   = (const float*)d_in[2];
    const float* h0     = (const float*)d_in[3];
    const float* c0     = (const float*)d_in[4];
    const float* W_va1  = (const float*)d_in[5];
    const float* W_va2  = (const float*)d_in[6];
    const float* W_va3  = (const float*)d_in[7];
    const float* W_venc = (const float*)d_in[8];
    const float* W_aa1  = (const float*)d_in[9];
    const float* W_aa2  = (const float*)d_in[10];
    const float* W_aa3  = (const float*)d_in[11];
    const float* W_aenc = (const float*)d_in[12];
    const float* W_ca1  = (const float*)d_in[13];
    const float* W_ca2  = (const float*)d_in[14];
    const float* W_ca3  = (const float*)d_in[15];
    const float* W_ih   = (const float*)d_in[16];
    const float* W_hh   = (const float*)d_in[17];
    const float* b_ih   = (const float*)d_in[18];
    const float* b_hh   = (const float*)d_in[19];
    const float* W_out  = (const float*)d_in[20];
    const float* b_out  = (const float*)d_in[21];
    float* out = (float*)d_out;

    // workspace layout: [zero-initialized region | plain scratch]
    float* ws = (float*)d_ws;
    float* hv1  = ws;  ws += 128 * 512;                 // zeroed (atomic targets)
    float* ha1  = ws;  ws += 128 * 512;
    float* hc1  = ws;  ws += 128 * 512;
    float* scv  = ws;  ws += 128 * 64;
    float* sca  = ws;  ws += 128 * 128;
    float* ctx  = ws;  ws += 128 * 2 * 512;
    float* v2c  = ws;  ws += 128 * 2 * 512;
    float* gates= ws;  ws += (size_t)128 * 4096;
    size_t zero_floats = (size_t)(ws - (float*)d_ws);
    float* xb   = ws;  ws += 128 * 1024;
    float* attv = ws;  ws += 128 * 1024;
    float* atta = ws;  ws += 128 * 512;

    dim3 blk(256);

    // 0. zero all atomic-accumulation targets + the logits output region
    hipMemsetAsync(d_ws, 0, zero_floats * sizeof(float), stream);
    hipMemsetAsync(out, 0, (size_t)128 * 20000 * sizeof(float), stream);

    // 1. three h0 projections, one MFMA launch: grid (24, 8) = 192 blocks
    hproj3_mfma<<<dim3(24, 8), blk, 0, stream>>>(h0, W_va1, W_aa1, W_ca1, hv1);
    // 2. both encoder projections + fused tanh-scores: 768 blocks, one launch
    scores_fused<<<dim3(768), blk, 0, stream>>>(encv, W_va2, hv1, W_va3, scv,
                                                enca, W_aa2, ha1, W_aa3, sca);
    // 3. softmax + weighted encoder sum, both modalities: grid (128, 6)
    attend_out2<<<dim3(128, 6), blk, 0, stream>>>(scv, encv, attv, sca, enca, atta);
    // 4. both context projections -> ctx[B,2,C]: grid (8,8,2) = 128 blocks
    ctxproj_mfma<<<dim3(8, 8, 2), blk, 0, stream>>>(attv, W_venc, atta, W_aenc, ctx);
    // 5. cross-modal key projection: split-K 4 -> 128 blocks
    gemm_sk<<<dim3(8, 4, 2), blk, 0, stream>>>(ctx, W_ca2, nullptr, v2c, 512, 512, 128, 512);
    // 6. cross-modal attention + x build
    cross_kernel<<<128, blk, 0, stream>>>(hc1, v2c, W_ca3, ctx, inp, xb);
    // 7. LSTM gates: both GEMMs, split-K 4 each: grid (64, 8) = 512 blocks
    gates_mfma<<<dim3(64, 8), blk, 0, stream>>>(xb, W_ih, h0, W_hh, gates);
    // 8. LSTM pointwise (+biases) -> h_new, c_new in d_out tail
    float* hout = out + 2560000;
    float* cout = out + 2560000 + 131072;
    lstm_kernel<<<512, blk, 0, stream>>>(gates, c0, b_ih, b_hh, hout, cout);
    // 9. logits: split-K 2, bias added by chunk 0. grid (313, 2) = 626 blocks
    gemm_sk<<<dim3(313, 2, 1), blk, 0, stream>>>(hout, W_out, b_out, out, 20000, 1024, 512, 20000);
}

// Round 2
// 388.167 us; speedup vs baseline: 1.0632x; 1.0632x over previous
//
#include <hip/hip_runtime.h>
#include <hip/hip_bf16.h>
#include <cstddef>

typedef __attribute__((ext_vector_type(8))) short short8;   // 8 bf16 = 4 VGPR
typedef __attribute__((ext_vector_type(4))) float f32x4;

static __device__ __forceinline__ short8 pack8(float4 f0, float4 f1) {
    union { __hip_bfloat162 h[4]; short8 s; } u;
    u.h[0] = __float22bfloat162_rn(make_float2(f0.x, f0.y));
    u.h[1] = __float22bfloat162_rn(make_float2(f0.z, f0.w));
    u.h[2] = __float22bfloat162_rn(make_float2(f1.x, f1.y));
    u.h[3] = __float22bfloat162_rn(make_float2(f1.z, f1.w));
    return u.s;
}

// ===========================================================================
// Generic split-K bf16 MFMA body: adds A[m0:m0+128, kbeg:kend] @ W^T tile
// into C via atomicAdd. Tile 128(M) x 64(N), BK=32, 256 thr (4 waves, each
// 32 rows x 64 cols). N bounds-checked. C must be zero-initialized.
// Round-2 structure: bf16 LDS double-buffer, XOR-swizzled 16B slots
// (phys = logical ^ ((row>>1)&3), stride 32 bf16 -- measured 0 conflicts),
// register prefetch of next K-tile, ONE barrier per K-step.
// ===========================================================================
static __device__ __forceinline__ void sk_body(
    const float* __restrict__ A, int lda,
    const float* __restrict__ W,
    const float* __restrict__ bias, int addbias,
    float* __restrict__ C, int ldc, int N,
    int kbeg, int kend, int n0, int m0)
{
    __shared__ short As[2][128 * 32];
    __shared__ short Ws[2][64 * 32];
    const int tid  = threadIdx.x;
    const int lane = tid & 63;
    const int wave = tid >> 6;
    const int wm = wave * 32;

    f32x4 acc[2][4];
    #pragma unroll
    for (int i = 0; i < 2; ++i)
        #pragma unroll
        for (int j = 0; j < 4; ++j)
            acc[i][j] = (f32x4){0.f, 0.f, 0.f, 0.f};

    // A staging: row = tid>>1 (0..127), k-half = tid&1 -> slots 2h, 2h+1
    const int arow = tid >> 1;
    const int ah   = tid & 1;
    const int afs  = (arow >> 1) & 3;
    const float* gA = A + (size_t)(m0 + arow) * lda + kbeg + ah * 16;
    const int aoff0 = arow * 32 + (((ah * 2)     ^ afs) * 8);
    const int aoff1 = arow * 32 + (((ah * 2 + 1) ^ afs) * 8);

    // W staging: row = tid>>2 (0..63), slot = tid&3
    const int wrow  = tid >> 2;
    const int wslot = tid & 3;
    const int wvalid = (n0 + wrow) < N;
    const float* gW = W + (size_t)(n0 + wrow) * lda + kbeg + wslot * 8;
    const int woff = wrow * 32 + ((wslot ^ ((wrow >> 1) & 3)) * 8);

    // fragment read offsets (wm, i*16, j*16 are multiples of 16 -> xor from frow only)
    const int frow = lane & 15;
    const int hi   = lane >> 4;
    const int fsl  = (hi ^ ((frow >> 1) & 3)) * 8;
    const int ra   = (wm + frow) * 32 + fsl;
    const int rb   = frow * 32 + fsl;

    // prologue: K-tile 0 into registers
    float4 pa0, pa1, pa2, pa3, pw0, pw1;
    pa0 = *(const float4*)(gA);      pa1 = *(const float4*)(gA + 4);
    pa2 = *(const float4*)(gA + 8);  pa3 = *(const float4*)(gA + 12);
    if (wvalid) { pw0 = *(const float4*)(gW); pw1 = *(const float4*)(gW + 4); }
    else        { pw0 = make_float4(0,0,0,0); pw1 = make_float4(0,0,0,0); }

    const int nsteps = (kend - kbeg) >> 5;
    for (int s = 0; s < nsteps; ++s) {
        short* as = As[s & 1];
        short* ws = Ws[s & 1];
        *(short8*)(as + aoff0) = pack8(pa0, pa1);
        *(short8*)(as + aoff1) = pack8(pa2, pa3);
        *(short8*)(ws + woff)  = pack8(pw0, pw1);
        if (s + 1 < nsteps) {     // issue next-tile loads; land under MFMA phase
            const float* nA = gA + (s + 1) * 32;
            pa0 = *(const float4*)(nA);      pa1 = *(const float4*)(nA + 4);
            pa2 = *(const float4*)(nA + 8);  pa3 = *(const float4*)(nA + 12);
            if (wvalid) {
                const float* nW = gW + (s + 1) * 32;
                pw0 = *(const float4*)(nW); pw1 = *(const float4*)(nW + 4);
            }
        }
        __syncthreads();
        short8 af[2], bf[4];
        #pragma unroll
        for (int i = 0; i < 2; ++i)
            af[i] = *(const short8*)(as + ra + i * 512);
        #pragma unroll
        for (int j = 0; j < 4; ++j)
            bf[j] = *(const short8*)(ws + rb + j * 512);
        #pragma unroll
        for (int i = 0; i < 2; ++i)
            #pragma unroll
            for (int j = 0; j < 4; ++j)
                acc[i][j] = __builtin_amdgcn_mfma_f32_16x16x32_bf16(af[i], bf[j], acc[i][j], 0, 0, 0);
        // no second barrier: next iter writes the OTHER buffer
    }

    const int cl = lane & 15;
    const int rq = hi * 4;
    #pragma unroll
    for (int j = 0; j < 4; ++j) {
        int gc = n0 + j * 16 + cl;
        if (gc >= N) continue;
        float b = addbias ? bias[gc] : 0.f;
        #pragma unroll
        for (int i = 0; i < 2; ++i) {
            int gr = m0 + wm + i * 16 + rq;
            #pragma unroll
            for (int r = 0; r < 4; ++r)
                atomicAdd(C + (size_t)(gr + r) * ldc + gc, acc[i][j][r] + b);
        }
    }
}

// generic wrapper: grid (ceil(N/64), ksplit, M/128)
__global__ __launch_bounds__(256) void gemm_sk(
    const float* __restrict__ A, const float* __restrict__ W,
    const float* __restrict__ bias, float* __restrict__ C,
    int N, int K, int kchunk, int ldc)
{
    int kbeg = blockIdx.y * kchunk;
    sk_body(A, K, W, bias, bias != nullptr && blockIdx.y == 0,
            C, ldc, N, kbeg, kbeg + kchunk, blockIdx.x * 64, blockIdx.z * 128);
}

// three h0 projections fused: weight/output selected by n-tile. grid (24,8)
__global__ __launch_bounds__(256) void hproj3_mfma(
    const float* __restrict__ h0,
    const float* __restrict__ Wa, const float* __restrict__ Wb, const float* __restrict__ Wc,
    float* __restrict__ hbase)
{
    int n0g = blockIdx.x * 64;
    int wsel = n0g >> 9;
    const float* W = (wsel == 0) ? Wa : (wsel == 1) ? Wb : Wc;
    float* C = hbase + (size_t)wsel * 128 * 512;
    int kbeg = blockIdx.y * 128;
    sk_body(h0, 1024, W, nullptr, 0, C, 512, 512, kbeg, kbeg + 128, n0g & 511, 0);
}

// both context projections fused into ctx[B,2,C]. grid (8,8,2)
__global__ __launch_bounds__(256) void ctxproj_mfma(
    const float* __restrict__ attv, const float* __restrict__ Wv,
    const float* __restrict__ atta, const float* __restrict__ Wa,
    float* __restrict__ ctx)
{
    const float* A; const float* W; float* C; int lda, kb, ke;
    if (blockIdx.z == 0) { A = attv; W = Wv; C = ctx;       lda = 1024; kb = blockIdx.y * 128; ke = kb + 128; }
    else                 { A = atta; W = Wa; C = ctx + 512; lda = 512;  kb = blockIdx.y * 64;  ke = kb + 64;  }
    sk_body(A, lda, W, nullptr, 0, C, 1024, 512, kb, ke, blockIdx.x * 64, 0);
}

// both LSTM gate GEMMs fused (biases applied in lstm_kernel). grid (64,8)
__global__ __launch_bounds__(256) void gates_mfma(
    const float* __restrict__ xb, const float* __restrict__ W_ih,
    const float* __restrict__ h0, const float* __restrict__ W_hh,
    float* __restrict__ gates)
{
    int pair = blockIdx.y >> 2;
    const float* A = pair ? h0 : xb;
    const float* W = pair ? W_hh : W_ih;
    int kb = (blockIdx.y & 3) * 256;
    sk_body(A, 1024, W, nullptr, 0, gates, 4096, 4096, kb, kb + 256, blockIdx.x * 64, 0);
}

// ===========================================================================
// Fused encoder-projection + attention-score kernel, BOTH modalities in one
// launch. Round-2: tile back to 64(M) x 128(N) (1536 blocks -- occupancy is
// the binding constraint, proven by round-1 regression), KEEP the XOR LDS
// swizzle (round-1 measured 0 bank conflicts), add bf16 LDS double-buffer +
// register prefetch with ONE barrier per K-step.
// Epilogue: p = sum_cols tanh(v1+v2)*W3, reduce 16 col-lanes, atomicAdd
// into sc[row]. N=512 exactly (4 n-tiles, no bounds checks).
// Block order n-major: all n-users of an A-tile land on the same XCD.
// grid: 512 visual blocks (n*128+m) then 1024 audio blocks (512 + n*256+m).
// ===========================================================================
__global__ __launch_bounds__(256) void scores_fused(
    const float* __restrict__ encv, const float* __restrict__ W_va2,
    const float* __restrict__ hv1,  const float* __restrict__ W_va3,
    float* __restrict__ scv,
    const float* __restrict__ enca, const float* __restrict__ W_aa2,
    const float* __restrict__ ha1,  const float* __restrict__ W_aa3,
    float* __restrict__ sca)
{
    __shared__ short As[2][64 * 32];
    __shared__ short Ws[2][128 * 32];

    const float *A, *W, *v1, *W3;
    float* sc;
    int K, tshift, n0, m0;
    int idx = blockIdx.x;
    if (idx < 512) {            // visual: M=8192, K=1024, T=64
        n0 = (idx >> 7) * 128;  m0 = (idx & 127) * 64;
        A = encv; W = W_va2; v1 = hv1; W3 = W_va3; sc = scv;
        K = 1024; tshift = 6;
    } else {                    // audio: M=16384, K=512, T=128
        idx -= 512;
        n0 = (idx >> 8) * 128;  m0 = (idx & 255) * 64;
        A = enca; W = W_aa2; v1 = ha1; W3 = W_aa3; sc = sca;
        K = 512; tshift = 7;
    }

    const int tid  = threadIdx.x;
    const int lane = tid & 63;
    const int wave = tid >> 6;
    const int wm = (wave >> 1) * 32;
    const int wn = (wave & 1) * 64;

    f32x4 acc[2][4];
    #pragma unroll
    for (int i = 0; i < 2; ++i)
        #pragma unroll
        for (int j = 0; j < 4; ++j)
            acc[i][j] = (f32x4){0.f, 0.f, 0.f, 0.f};

    // A staging: row = tid>>2 (0..63), slot = tid&3
    const int arow  = tid >> 2;
    const int aslot = tid & 3;
    const float* gA = A + (size_t)(m0 + arow) * K + aslot * 8;
    const int aoff  = arow * 32 + ((aslot ^ ((arow >> 1) & 3)) * 8);

    // W staging: row = tid>>1 (0..127), k-half = tid&1 -> slots 2h, 2h+1
    const int wrow = tid >> 1;
    const int wh   = tid & 1;
    const int wfs  = (wrow >> 1) & 3;
    const float* gW = W + (size_t)(n0 + wrow) * K + wh * 16;
    const int woff0 = wrow * 32 + (((wh * 2)     ^ wfs) * 8);
    const int woff1 = wrow * 32 + (((wh * 2 + 1) ^ wfs) * 8);

    // fragment read offsets
    const int frow = lane & 15;
    const int hi   = lane >> 4;
    const int fsl  = (hi ^ ((frow >> 1) & 3)) * 8;
    const int ra   = (wm + frow) * 32 + fsl;
    const int rb   = (wn + frow) * 32 + fsl;

    // prologue: K-tile 0 into registers
    float4 pa0, pa1, pw0, pw1, pw2, pw3;
    pa0 = *(const float4*)(gA);      pa1 = *(const float4*)(gA + 4);
    pw0 = *(const float4*)(gW);      pw1 = *(const float4*)(gW + 4);
    pw2 = *(const float4*)(gW + 8);  pw3 = *(const float4*)(gW + 12);

    const int nsteps = K >> 5;
    for (int s = 0; s < nsteps; ++s) {
        short* as = As[s & 1];
        short* ws = Ws[s & 1];
        *(short8*)(as + aoff)  = pack8(pa0, pa1);
        *(short8*)(ws + woff0) = pack8(pw0, pw1);
        *(short8*)(ws + woff1) = pack8(pw2, pw3);
        if (s + 1 < nsteps) {     // issue next-tile loads; land under MFMA phase
            const float* nA = gA + (s + 1) * 32;
            pa0 = *(const float4*)(nA);      pa1 = *(const float4*)(nA + 4);
            const float* nW = gW + (s + 1) * 32;
            pw0 = *(const float4*)(nW);      pw1 = *(const float4*)(nW + 4);
            pw2 = *(const float4*)(nW + 8);  pw3 = *(const float4*)(nW + 12);
        }
        __syncthreads();
        short8 af[2], bf[4];
        #pragma unroll
        for (int i = 0; i < 2; ++i)
            af[i] = *(const short8*)(as + ra + i * 512);
        #pragma unroll
        for (int j = 0; j < 4; ++j)
            bf[j] = *(const short8*)(ws + rb + j * 512);
        #pragma unroll
        for (int i = 0; i < 2; ++i)
            #pragma unroll
            for (int j = 0; j < 4; ++j)
                acc[i][j] = __builtin_amdgcn_mfma_f32_16x16x32_bf16(af[i], bf[j], acc[i][j], 0, 0, 0);
        // no second barrier: next iter writes the OTHER buffer
    }

    // epilogue: p = sum_cols tanh(v1[b,c] + v2) * W3[c]; reduce 16 col-lanes
    const int cl = lane & 15;
    const int rq = hi * 4;
    #pragma unroll
    for (int i = 0; i < 2; ++i) {
        #pragma unroll
        for (int r = 0; r < 4; ++r) {
            int gr = m0 + wm + i * 16 + rq + r;
            const float* v1row = v1 + (size_t)(gr >> tshift) * 512;
            float p = 0.f;
            #pragma unroll
            for (int j = 0; j < 4; ++j) {
                int gc = n0 + wn + j * 16 + cl;
                p += tanhf(v1row[gc] + acc[i][j][r]) * W3[gc];
            }
            p += __shfl_xor(p, 1, 64);
            p += __shfl_xor(p, 2, 64);
            p += __shfl_xor(p, 4, 64);
            p += __shfl_xor(p, 8, 64);
            if (cl == 0) atomicAdd(sc + gr, p);
        }
    }
}

// ===========================================================================
// Softmax over T + weighted sum, both modalities in one launch.
// grid (B, 6): y<4 -> visual e-chunk y; y>=4 -> audio e-chunk y-4.
// ===========================================================================
__global__ __launch_bounds__(256) void attend_out2(
    const float* __restrict__ scv, const float* __restrict__ encv, float* __restrict__ attv,
    const float* __restrict__ sca, const float* __restrict__ enca, float* __restrict__ atta)
{
    const float* sc; const float* enc; float* out;
    int T, E, ec;
    if (blockIdx.y < 4) { sc = scv; enc = encv; out = attv; T = 64;  E = 1024; ec = blockIdx.y; }
    else                { sc = sca; enc = enca; out = atta; T = 128; E = 512;  ec = blockIdx.y - 4; }

    __shared__ float ew[128];
    const int b = blockIdx.x, tid = threadIdx.x;
    __shared__ float raw[128];
    if (tid < T) raw[tid] = sc[(size_t)b * T + tid];
    __syncthreads();
    float m = -1e30f;
    for (int t = 0; t < T; ++t) m = fmaxf(m, raw[t]);
    if (tid < T) ew[tid] = __expf(raw[tid] - m);
    __syncthreads();
    float sum = 0.f;
    for (int t = 0; t < T; ++t) sum += ew[t];
    const float inv = 1.f / sum;

    const int e = ec * 256 + tid;
    const float* encb = enc + (size_t)b * T * E + e;
    float acc = 0.f;
    for (int t = 0; t < T; ++t)
        acc += ew[t] * encb[(size_t)t * E];
    out[(size_t)b * E + e] = acc * inv;
}

// ===========================================================================
// Cross-modal attention + build x = [input | tanh(final_ctx)]
// ===========================================================================
__global__ __launch_bounds__(256) void cross_kernel(
    const float* __restrict__ hc1, const float* __restrict__ v2c,
    const float* __restrict__ W3, const float* __restrict__ ctx,
    const float* __restrict__ inp, float* __restrict__ x)
{
    const int C = 512;
    __shared__ float red[256];
    __shared__ float aw[2];
    const int b = blockIdx.x, tid = threadIdx.x;

    float p0 = 0.f, p1 = 0.f;
    for (int c = tid; c < C; c += 256) {
        float h = hc1[(size_t)b * C + c], w = W3[c];
        p0 += tanhf(h + v2c[(size_t)(b * 2 + 0) * C + c]) * w;
        p1 += tanhf(h + v2c[(size_t)(b * 2 + 1) * C + c]) * w;
    }
    red[tid] = p0; __syncthreads();
    for (int s = 128; s; s >>= 1) { if (tid < s) red[tid] += red[tid + s]; __syncthreads(); }
    float s0 = red[0];
    __syncthreads();
    red[tid] = p1; __syncthreads();
    for (int s = 128; s; s >>= 1) { if (tid < s) red[tid] += red[tid + s]; __syncthreads(); }
    if (tid == 0) {
        float s1 = red[0];
        float m = fmaxf(s0, s1);
        float e0 = __expf(s0 - m), e1 = __expf(s1 - m);
        float inv = 1.f / (e0 + e1);
        aw[0] = e0 * inv; aw[1] = e1 * inv;
    }
    __syncthreads();
    float a0 = aw[0], a1 = aw[1];
    for (int c = tid; c < C; c += 256) {
        float fc = a0 * ctx[(size_t)(b * 2 + 0) * C + c]
                 + a1 * ctx[(size_t)(b * 2 + 1) * C + c];
        x[(size_t)b * 1024 + 512 + c] = tanhf(fc);
        x[(size_t)b * 1024 + c] = inp[(size_t)b * 512 + c];
    }
}

// ===========================================================================
// LSTM pointwise (biases folded in here)
// ===========================================================================
__global__ __launch_bounds__(256) void lstm_kernel(
    const float* __restrict__ gates, const float* __restrict__ c0,
    const float* __restrict__ b_ih, const float* __restrict__ b_hh,
    float* __restrict__ hout, float* __restrict__ cout)
{
    const int idx = blockIdx.x * 256 + threadIdx.x;   // B*H = 131072
    const int b = idx >> 10, h = idx & 1023;
    const float* g = gates + (size_t)b * 4096;
    float gi = g[h]        + b_ih[h]        + b_hh[h];
    float gf = g[1024 + h] + b_ih[1024 + h] + b_hh[1024 + h];
    float gg = g[2048 + h] + b_ih[2048 + h] + b_hh[2048 + h];
    float go = g[3072 + h] + b_ih[3072 + h] + b_hh[3072 + h];
    float si = 1.f / (1.f + __expf(-gi));
    float sf = 1.f / (1.f + __expf(-gf));
    float so = 1.f / (1.f + __expf(-go));
    float cn = sf * c0[idx] + si * tanhf(gg);
    float hn = so * tanhf(cn);
    cout[idx] = cn;
    hout[idx] = hn;
}

// ---------------------------------------------------------------------------
extern "C" void kernel_launch(void* const* d_in, const int* in_sizes, int n_in,
                              void* d_out, int out_size, void* d_ws, size_t ws_size,
                              hipStream_t stream)
{
    const float* inp    = (const float*)d_in[0];
    const float* encv   = (const float*)d_in[1];
    const float* enca   = (const float*)d_in[2];
    const float* h0     = (const float*)d_in[3];
    const float* c0     = (const float*)d_in[4];
    const float* W_va1  = (const float*)d_in[5];
    const float* W_va2  = (const float*)d_in[6];
    const float* W_va3  = (const float*)d_in[7];
    const float* W_venc = (const float*)d_in[8];
    const float* W_aa1  = (const float*)d_in[9];
    const float* W_aa2  = (const float*)d_in[10];
    const float* W_aa3  = (const float*)d_in[11];
    const float* W_aenc = (const float*)d_in[12];
    const float* W_ca1  = (const float*)d_in[13];
    const float* W_ca2  = (const float*)d_in[14];
    const float* W_ca3  = (const float*)d_in[15];
    const float* W_ih   = (const float*)d_in[16];
    const float* W_hh   = (const float*)d_in[17];
    const float* b_ih   = (const float*)d_in[18];
    const float* b_hh   = (const float*)d_in[19];
    const float* W_out  = (const float*)d_in[20];
    const float* b_out  = (const float*)d_in[21];
    float* out = (float*)d_out;

    // workspace layout: [zero-initialized region | plain scratch]
    float* ws = (float*)d_ws;
    float* hv1  = ws;  ws += 128 * 512;                 // zeroed (atomic targets)
    float* ha1  = ws;  ws += 128 * 512;
    float* hc1  = ws;  ws += 128 * 512;
    float* scv  = ws;  ws += 128 * 64;
    float* sca  = ws;  ws += 128 * 128;
    float* ctx  = ws;  ws += 128 * 2 * 512;
    float* v2c  = ws;  ws += 128 * 2 * 512;
    float* gates= ws;  ws += (size_t)128 * 4096;
    size_t zero_floats = (size_t)(ws - (float*)d_ws);
    float* xb   = ws;  ws += 128 * 1024;
    float* attv = ws;  ws += 128 * 1024;
    float* atta = ws;  ws += 128 * 512;

    dim3 blk(256);

    // 0. zero all atomic-accumulation targets + the logits output region
    hipMemsetAsync(d_ws, 0, zero_floats * sizeof(float), stream);
    hipMemsetAsync(out, 0, (size_t)128 * 20000 * sizeof(float), stream);

    // 1. three h0 projections, one MFMA launch: grid (24, 8) = 192 blocks
    hproj3_mfma<<<dim3(24, 8), blk, 0, stream>>>(h0, W_va1, W_aa1, W_ca1, hv1);
    // 2. both encoder projections + fused tanh-scores: 1536 blocks, one launch
    scores_fused<<<dim3(1536), blk, 0, stream>>>(encv, W_va2, hv1, W_va3, scv,
                                                 enca, W_aa2, ha1, W_aa3, sca);
    // 3. softmax + weighted encoder sum, both modalities: grid (128, 6)
    attend_out2<<<dim3(128, 6), blk, 0, stream>>>(scv, encv, attv, sca, enca, atta);
    // 4. both context projections -> ctx[B,2,C]: grid (8,8,2) = 128 blocks
    ctxproj_mfma<<<dim3(8, 8, 2), blk, 0, stream>>>(attv, W_venc, atta, W_aenc, ctx);
    // 5. cross-modal key projection: split-K 4 -> 128 blocks
    gemm_sk<<<dim3(8, 4, 2), blk, 0, stream>>>(ctx, W_ca2, nullptr, v2c, 512, 512, 128, 512);
    // 6. cross-modal attention + x build
    cross_kernel<<<128, blk, 0, stream>>>(hc1, v2c, W_ca3, ctx, inp, xb);
    // 7. LSTM gates: both GEMMs, split-K 4 each: grid (64, 8) = 512 blocks
    gates_mfma<<<dim3(64, 8), blk, 0, stream>>>(xb, W_ih, h0, W_hh, gates);
    // 8. LSTM pointwise (+biases) -> h_new, c_new in d_out tail
    float* hout = out + 2560000;
    float* cout = out + 2560000 + 131072;
    lstm_kernel<<<512, blk, 0, stream>>>(gates, c0, b_ih, b_hh, hout, cout);
    // 9. logits: split-K 2, bias added by chunk 0. grid (313, 2) = 626 blocks
    gemm_sk<<<dim3(313, 2, 1), blk, 0, stream>>>(hout, W_out, b_out, out, 20000, 1024, 512, 20000);
}

// Round 3
// 379.737 us; speedup vs baseline: 1.0868x; 1.0222x over previous
//
#include <hip/hip_runtime.h>
#include <hip/hip_bf16.h>
#include <cstddef>

typedef __attribute__((ext_vector_type(8))) short short8;   // 8 bf16 = 4 VGPR
typedef __attribute__((ext_vector_type(4))) float f32x4;

static __device__ __forceinline__ short8 pack8(float4 f0, float4 f1) {
    union { __hip_bfloat162 h[4]; short8 s; } u;
    u.h[0] = __float22bfloat162_rn(make_float2(f0.x, f0.y));
    u.h[1] = __float22bfloat162_rn(make_float2(f0.z, f0.w));
    u.h[2] = __float22bfloat162_rn(make_float2(f1.x, f1.y));
    u.h[3] = __float22bfloat162_rn(make_float2(f1.z, f1.w));
    return u.s;
}

// ===========================================================================
// Generic split-K bf16 MFMA body: adds A[m0:m0+128, kbeg:kend] @ W^T tile
// into C via atomicAdd. Tile 128(M) x 64(N), BK=32, 256 thr (4 waves, each
// 32 rows x 64 cols). N bounds-checked. C must be zero-initialized.
// Round-3: prefetch DEPTH 2 (two register tile-sets, even/odd static unroll)
// -> 2x outstanding HBM bytes per wave; LDS bf16 double-buffer with XOR
// swizzle (0 conflicts measured); ONE barrier per K-step.
// Requires nsteps even and >= 2 (all call sites satisfy this).
// ===========================================================================
static __device__ __forceinline__ void sk_body(
    const float* __restrict__ A, int lda,
    const float* __restrict__ W,
    const float* __restrict__ bias, int addbias,
    float* __restrict__ C, int ldc, int N,
    int kbeg, int kend, int n0, int m0)
{
    __shared__ short As[2][128 * 32];
    __shared__ short Ws[2][64 * 32];
    const int tid  = threadIdx.x;
    const int lane = tid & 63;
    const int wave = tid >> 6;
    const int wm = wave * 32;

    f32x4 acc[2][4];
    #pragma unroll
    for (int i = 0; i < 2; ++i)
        #pragma unroll
        for (int j = 0; j < 4; ++j)
            acc[i][j] = (f32x4){0.f, 0.f, 0.f, 0.f};

    // A staging: row = tid>>1 (0..127), k-half = tid&1 -> slots 2h, 2h+1
    const int arow = tid >> 1;
    const int ah   = tid & 1;
    const int afs  = (arow >> 1) & 3;
    const float* gA = A + (size_t)(m0 + arow) * lda + kbeg + ah * 16;
    const int aoff0 = arow * 32 + (((ah * 2)     ^ afs) * 8);
    const int aoff1 = arow * 32 + (((ah * 2 + 1) ^ afs) * 8);

    // W staging: row = tid>>2 (0..63), slot = tid&3
    const int wrow  = tid >> 2;
    const int wslot = tid & 3;
    const int wvalid = (n0 + wrow) < N;
    const float* gW = W + (size_t)(n0 + wrow) * lda + kbeg + wslot * 8;
    const int woff = wrow * 32 + ((wslot ^ ((wrow >> 1) & 3)) * 8);

    // fragment read offsets
    const int frow = lane & 15;
    const int hi   = lane >> 4;
    const int fsl  = (hi ^ ((frow >> 1) & 3)) * 8;
    const int ra   = (wm + frow) * 32 + fsl;
    const int rb   = frow * 32 + fsl;

    const int nsteps = (kend - kbeg) >> 5;

    // prologue: K-tiles 0 and 1 into two register sets
    float4 a0_[4], a1_[4], w0_[2], w1_[2];
    #pragma unroll
    for (int q = 0; q < 4; ++q) a0_[q] = *(const float4*)(gA + q * 4);
    #pragma unroll
    for (int q = 0; q < 4; ++q) a1_[q] = *(const float4*)(gA + 32 + q * 4);
    if (wvalid) {
        w0_[0] = *(const float4*)(gW);      w0_[1] = *(const float4*)(gW + 4);
        w1_[0] = *(const float4*)(gW + 32); w1_[1] = *(const float4*)(gW + 36);
    } else {
        w0_[0] = w0_[1] = w1_[0] = w1_[1] = make_float4(0, 0, 0, 0);
    }

    for (int s = 0; s < nsteps; s += 2) {
        // ---- even step: consume set 0 into buf 0, reload set 0 from s+2 ----
        {
            short* as = As[0]; short* ws = Ws[0];
            *(short8*)(as + aoff0) = pack8(a0_[0], a0_[1]);
            *(short8*)(as + aoff1) = pack8(a0_[2], a0_[3]);
            *(short8*)(ws + woff)  = pack8(w0_[0], w0_[1]);
            if (s + 2 < nsteps) {
                const float* nA = gA + (s + 2) * 32;
                #pragma unroll
                for (int q = 0; q < 4; ++q) a0_[q] = *(const float4*)(nA + q * 4);
                if (wvalid) {
                    const float* nW = gW + (s + 2) * 32;
                    w0_[0] = *(const float4*)(nW); w0_[1] = *(const float4*)(nW + 4);
                }
            }
            __syncthreads();
            short8 af[2], bf[4];
            #pragma unroll
            for (int i = 0; i < 2; ++i) af[i] = *(const short8*)(as + ra + i * 512);
            #pragma unroll
            for (int j = 0; j < 4; ++j) bf[j] = *(const short8*)(ws + rb + j * 512);
            #pragma unroll
            for (int i = 0; i < 2; ++i)
                #pragma unroll
                for (int j = 0; j < 4; ++j)
                    acc[i][j] = __builtin_amdgcn_mfma_f32_16x16x32_bf16(af[i], bf[j], acc[i][j], 0, 0, 0);
        }
        // ---- odd step: consume set 1 into buf 1, reload set 1 from s+3 ----
        {
            short* as = As[1]; short* ws = Ws[1];
            *(short8*)(as + aoff0) = pack8(a1_[0], a1_[1]);
            *(short8*)(as + aoff1) = pack8(a1_[2], a1_[3]);
            *(short8*)(ws + woff)  = pack8(w1_[0], w1_[1]);
            if (s + 3 < nsteps) {
                const float* nA = gA + (s + 3) * 32;
                #pragma unroll
                for (int q = 0; q < 4; ++q) a1_[q] = *(const float4*)(nA + q * 4);
                if (wvalid) {
                    const float* nW = gW + (s + 3) * 32;
                    w1_[0] = *(const float4*)(nW); w1_[1] = *(const float4*)(nW + 4);
                }
            }
            __syncthreads();
            short8 af[2], bf[4];
            #pragma unroll
            for (int i = 0; i < 2; ++i) af[i] = *(const short8*)(as + ra + i * 512);
            #pragma unroll
            for (int j = 0; j < 4; ++j) bf[j] = *(const short8*)(ws + rb + j * 512);
            #pragma unroll
            for (int i = 0; i < 2; ++i)
                #pragma unroll
                for (int j = 0; j < 4; ++j)
                    acc[i][j] = __builtin_amdgcn_mfma_f32_16x16x32_bf16(af[i], bf[j], acc[i][j], 0, 0, 0);
        }
    }

    const int cl = lane & 15;
    const int rq = hi * 4;
    #pragma unroll
    for (int j = 0; j < 4; ++j) {
        int gc = n0 + j * 16 + cl;
        if (gc >= N) continue;
        float b = addbias ? bias[gc] : 0.f;
        #pragma unroll
        for (int i = 0; i < 2; ++i) {
            int gr = m0 + wm + i * 16 + rq;
            #pragma unroll
            for (int r = 0; r < 4; ++r)
                atomicAdd(C + (size_t)(gr + r) * ldc + gc, acc[i][j][r] + b);
        }
    }
}

// generic wrapper: grid (ceil(N/64), ksplit, M/128)
__global__ __launch_bounds__(256) void gemm_sk(
    const float* __restrict__ A, const float* __restrict__ W,
    const float* __restrict__ bias, float* __restrict__ C,
    int N, int K, int kchunk, int ldc)
{
    int kbeg = blockIdx.y * kchunk;
    sk_body(A, K, W, bias, bias != nullptr && blockIdx.y == 0,
            C, ldc, N, kbeg, kbeg + kchunk, blockIdx.x * 64, blockIdx.z * 128);
}

// three h0 projections fused: weight/output selected by n-tile. grid (24,8)
__global__ __launch_bounds__(256) void hproj3_mfma(
    const float* __restrict__ h0,
    const float* __restrict__ Wa, const float* __restrict__ Wb, const float* __restrict__ Wc,
    float* __restrict__ hbase)
{
    int n0g = blockIdx.x * 64;
    int wsel = n0g >> 9;
    const float* W = (wsel == 0) ? Wa : (wsel == 1) ? Wb : Wc;
    float* C = hbase + (size_t)wsel * 128 * 512;
    int kbeg = blockIdx.y * 128;
    sk_body(h0, 1024, W, nullptr, 0, C, 512, 512, kbeg, kbeg + 128, n0g & 511, 0);
}

// both context projections fused into ctx[B,2,C]. grid (8,8,2)
__global__ __launch_bounds__(256) void ctxproj_mfma(
    const float* __restrict__ attv, const float* __restrict__ Wv,
    const float* __restrict__ atta, const float* __restrict__ Wa,
    float* __restrict__ ctx)
{
    const float* A; const float* W; float* C; int lda, kb, ke;
    if (blockIdx.z == 0) { A = attv; W = Wv; C = ctx;       lda = 1024; kb = blockIdx.y * 128; ke = kb + 128; }
    else                 { A = atta; W = Wa; C = ctx + 512; lda = 512;  kb = blockIdx.y * 64;  ke = kb + 64;  }
    sk_body(A, lda, W, nullptr, 0, C, 1024, 512, kb, ke, blockIdx.x * 64, 0);
}

// both LSTM gate GEMMs fused (biases applied in lstm_kernel). grid (64,8)
__global__ __launch_bounds__(256) void gates_mfma(
    const float* __restrict__ xb, const float* __restrict__ W_ih,
    const float* __restrict__ h0, const float* __restrict__ W_hh,
    float* __restrict__ gates)
{
    int pair = blockIdx.y >> 2;
    const float* A = pair ? h0 : xb;
    const float* W = pair ? W_hh : W_ih;
    int kb = (blockIdx.y & 3) * 256;
    sk_body(A, 1024, W, nullptr, 0, gates, 4096, 4096, kb, kb + 256, blockIdx.x * 64, 0);
}

// ===========================================================================
// Fused encoder-projection + attention-score kernel, BOTH modalities in one
// launch. Tile 64(M) x 128(N), BK=32, 256 thr (4 waves 2x2: 32m x 64n each).
// Round-3: prefetch depth 2 (even/odd register sets), XOR-swizzled bf16 LDS
// double-buffer (0 conflicts), ONE barrier per K-step.
// Epilogue: p = sum_cols tanh(v1+v2)*W3, reduce 16 col-lanes, atomicAdd
// into sc[row]. N=512 exactly (4 n-tiles, no bounds checks).
// Block order n-major: all n-users of an A-tile land on the same XCD.
// grid: 512 visual blocks (n*128+m) then 1024 audio blocks (512 + n*256+m).
// ===========================================================================
__global__ __launch_bounds__(256) void scores_fused(
    const float* __restrict__ encv, const float* __restrict__ W_va2,
    const float* __restrict__ hv1,  const float* __restrict__ W_va3,
    float* __restrict__ scv,
    const float* __restrict__ enca, const float* __restrict__ W_aa2,
    const float* __restrict__ ha1,  const float* __restrict__ W_aa3,
    float* __restrict__ sca)
{
    __shared__ short As[2][64 * 32];
    __shared__ short Ws[2][128 * 32];

    const float *A, *W, *v1, *W3;
    float* sc;
    int K, tshift, n0, m0;
    int idx = blockIdx.x;
    if (idx < 512) {            // visual: M=8192, K=1024, T=64
        n0 = (idx >> 7) * 128;  m0 = (idx & 127) * 64;
        A = encv; W = W_va2; v1 = hv1; W3 = W_va3; sc = scv;
        K = 1024; tshift = 6;
    } else {                    // audio: M=16384, K=512, T=128
        idx -= 512;
        n0 = (idx >> 8) * 128;  m0 = (idx & 255) * 64;
        A = enca; W = W_aa2; v1 = ha1; W3 = W_aa3; sc = sca;
        K = 512; tshift = 7;
    }

    const int tid  = threadIdx.x;
    const int lane = tid & 63;
    const int wave = tid >> 6;
    const int wm = (wave >> 1) * 32;
    const int wn = (wave & 1) * 64;

    f32x4 acc[2][4];
    #pragma unroll
    for (int i = 0; i < 2; ++i)
        #pragma unroll
        for (int j = 0; j < 4; ++j)
            acc[i][j] = (f32x4){0.f, 0.f, 0.f, 0.f};

    // A staging: row = tid>>2 (0..63), slot = tid&3
    const int arow  = tid >> 2;
    const int aslot = tid & 3;
    const float* gA = A + (size_t)(m0 + arow) * K + aslot * 8;
    const int aoff  = arow * 32 + ((aslot ^ ((arow >> 1) & 3)) * 8);

    // W staging: row = tid>>1 (0..127), k-half = tid&1 -> slots 2h, 2h+1
    const int wrow = tid >> 1;
    const int wh   = tid & 1;
    const int wfs  = (wrow >> 1) & 3;
    const float* gW = W + (size_t)(n0 + wrow) * K + wh * 16;
    const int woff0 = wrow * 32 + (((wh * 2)     ^ wfs) * 8);
    const int woff1 = wrow * 32 + (((wh * 2 + 1) ^ wfs) * 8);

    // fragment read offsets
    const int frow = lane & 15;
    const int hi   = lane >> 4;
    const int fsl  = (hi ^ ((frow >> 1) & 3)) * 8;
    const int ra   = (wm + frow) * 32 + fsl;
    const int rb   = (wn + frow) * 32 + fsl;

    const int nsteps = K >> 5;

    // prologue: K-tiles 0 and 1 into two register sets
    float4 a0_[2], a1_[2], w0_[4], w1_[4];
    a0_[0] = *(const float4*)(gA);      a0_[1] = *(const float4*)(gA + 4);
    a1_[0] = *(const float4*)(gA + 32); a1_[1] = *(const float4*)(gA + 36);
    #pragma unroll
    for (int q = 0; q < 4; ++q) w0_[q] = *(const float4*)(gW + q * 4);
    #pragma unroll
    for (int q = 0; q < 4; ++q) w1_[q] = *(const float4*)(gW + 32 + q * 4);

    for (int s = 0; s < nsteps; s += 2) {
        // ---- even step: consume set 0 into buf 0, reload set 0 from s+2 ----
        {
            short* as = As[0]; short* ws = Ws[0];
            *(short8*)(as + aoff)  = pack8(a0_[0], a0_[1]);
            *(short8*)(ws + woff0) = pack8(w0_[0], w0_[1]);
            *(short8*)(ws + woff1) = pack8(w0_[2], w0_[3]);
            if (s + 2 < nsteps) {
                const float* nA = gA + (s + 2) * 32;
                a0_[0] = *(const float4*)(nA); a0_[1] = *(const float4*)(nA + 4);
                const float* nW = gW + (s + 2) * 32;
                #pragma unroll
                for (int q = 0; q < 4; ++q) w0_[q] = *(const float4*)(nW + q * 4);
            }
            __syncthreads();
            short8 af[2], bf[4];
            #pragma unroll
            for (int i = 0; i < 2; ++i) af[i] = *(const short8*)(as + ra + i * 512);
            #pragma unroll
            for (int j = 0; j < 4; ++j) bf[j] = *(const short8*)(ws + rb + j * 512);
            #pragma unroll
            for (int i = 0; i < 2; ++i)
                #pragma unroll
                for (int j = 0; j < 4; ++j)
                    acc[i][j] = __builtin_amdgcn_mfma_f32_16x16x32_bf16(af[i], bf[j], acc[i][j], 0, 0, 0);
        }
        // ---- odd step: consume set 1 into buf 1, reload set 1 from s+3 ----
        {
            short* as = As[1]; short* ws = Ws[1];
            *(short8*)(as + aoff)  = pack8(a1_[0], a1_[1]);
            *(short8*)(ws + woff0) = pack8(w1_[0], w1_[1]);
            *(short8*)(ws + woff1) = pack8(w1_[2], w1_[3]);
            if (s + 3 < nsteps) {
                const float* nA = gA + (s + 3) * 32;
                a1_[0] = *(const float4*)(nA); a1_[1] = *(const float4*)(nA + 4);
                const float* nW = gW + (s + 3) * 32;
                #pragma unroll
                for (int q = 0; q < 4; ++q) w1_[q] = *(const float4*)(nW + q * 4);
            }
            __syncthreads();
            short8 af[2], bf[4];
            #pragma unroll
            for (int i = 0; i < 2; ++i) af[i] = *(const short8*)(as + ra + i * 512);
            #pragma unroll
            for (int j = 0; j < 4; ++j) bf[j] = *(const short8*)(ws + rb + j * 512);
            #pragma unroll
            for (int i = 0; i < 2; ++i)
                #pragma unroll
                for (int j = 0; j < 4; ++j)
                    acc[i][j] = __builtin_amdgcn_mfma_f32_16x16x32_bf16(af[i], bf[j], acc[i][j], 0, 0, 0);
        }
    }

    // epilogue: p = sum_cols tanh(v1[b,c] + v2) * W3[c]; reduce 16 col-lanes
    const int cl = lane & 15;
    const int rq = hi * 4;
    #pragma unroll
    for (int i = 0; i < 2; ++i) {
        #pragma unroll
        for (int r = 0; r < 4; ++r) {
            int gr = m0 + wm + i * 16 + rq + r;
            const float* v1row = v1 + (size_t)(gr >> tshift) * 512;
            float p = 0.f;
            #pragma unroll
            for (int j = 0; j < 4; ++j) {
                int gc = n0 + wn + j * 16 + cl;
                p += tanhf(v1row[gc] + acc[i][j][r]) * W3[gc];
            }
            p += __shfl_xor(p, 1, 64);
            p += __shfl_xor(p, 2, 64);
            p += __shfl_xor(p, 4, 64);
            p += __shfl_xor(p, 8, 64);
            if (cl == 0) atomicAdd(sc + gr, p);
        }
    }
}

// ===========================================================================
// Softmax over T + weighted sum, both modalities in one launch.
// grid (B, 6): y<4 -> visual e-chunk y; y>=4 -> audio e-chunk y-4.
// ===========================================================================
__global__ __launch_bounds__(256) void attend_out2(
    const float* __restrict__ scv, const float* __restrict__ encv, float* __restrict__ attv,
    const float* __restrict__ sca, const float* __restrict__ enca, float* __restrict__ atta)
{
    const float* sc; const float* enc; float* out;
    int T, E, ec;
    if (blockIdx.y < 4) { sc = scv; enc = encv; out = attv; T = 64;  E = 1024; ec = blockIdx.y; }
    else                { sc = sca; enc = enca; out = atta; T = 128; E = 512;  ec = blockIdx.y - 4; }

    __shared__ float ew[128];
    const int b = blockIdx.x, tid = threadIdx.x;
    __shared__ float raw[128];
    if (tid < T) raw[tid] = sc[(size_t)b * T + tid];
    __syncthreads();
    float m = -1e30f;
    for (int t = 0; t < T; ++t) m = fmaxf(m, raw[t]);
    if (tid < T) ew[tid] = __expf(raw[tid] - m);
    __syncthreads();
    float sum = 0.f;
    for (int t = 0; t < T; ++t) sum += ew[t];
    const float inv = 1.f / sum;

    const int e = ec * 256 + tid;
    const float* encb = enc + (size_t)b * T * E + e;
    float acc = 0.f;
    for (int t = 0; t < T; ++t)
        acc += ew[t] * encb[(size_t)t * E];
    out[(size_t)b * E + e] = acc * inv;
}

// ===========================================================================
// Cross-modal attention + build x = [input | tanh(final_ctx)]
// ===========================================================================
__global__ __launch_bounds__(256) void cross_kernel(
    const float* __restrict__ hc1, const float* __restrict__ v2c,
    const float* __restrict__ W3, const float* __restrict__ ctx,
    const float* __restrict__ inp, float* __restrict__ x)
{
    const int C = 512;
    __shared__ float red[256];
    __shared__ float aw[2];
    const int b = blockIdx.x, tid = threadIdx.x;

    float p0 = 0.f, p1 = 0.f;
    for (int c = tid; c < C; c += 256) {
        float h = hc1[(size_t)b * C + c], w = W3[c];
        p0 += tanhf(h + v2c[(size_t)(b * 2 + 0) * C + c]) * w;
        p1 += tanhf(h + v2c[(size_t)(b * 2 + 1) * C + c]) * w;
    }
    red[tid] = p0; __syncthreads();
    for (int s = 128; s; s >>= 1) { if (tid < s) red[tid] += red[tid + s]; __syncthreads(); }
    float s0 = red[0];
    __syncthreads();
    red[tid] = p1; __syncthreads();
    for (int s = 128; s; s >>= 1) { if (tid < s) red[tid] += red[tid + s]; __syncthreads(); }
    if (tid == 0) {
        float s1 = red[0];
        float m = fmaxf(s0, s1);
        float e0 = __expf(s0 - m), e1 = __expf(s1 - m);
        float inv = 1.f / (e0 + e1);
        aw[0] = e0 * inv; aw[1] = e1 * inv;
    }
    __syncthreads();
    float a0 = aw[0], a1 = aw[1];
    for (int c = tid; c < C; c += 256) {
        float fc = a0 * ctx[(size_t)(b * 2 + 0) * C + c]
                 + a1 * ctx[(size_t)(b * 2 + 1) * C + c];
        x[(size_t)b * 1024 + 512 + c] = tanhf(fc);
        x[(size_t)b * 1024 + c] = inp[(size_t)b * 512 + c];
    }
}

// ===========================================================================
// LSTM pointwise (biases folded in here)
// ===========================================================================
__global__ __launch_bounds__(256) void lstm_kernel(
    const float* __restrict__ gates, const float* __restrict__ c0,
    const float* __restrict__ b_ih, const float* __restrict__ b_hh,
    float* __restrict__ hout, float* __restrict__ cout)
{
    const int idx = blockIdx.x * 256 + threadIdx.x;   // B*H = 131072
    const int b = idx >> 10, h = idx & 1023;
    const float* g = gates + (size_t)b * 4096;
    float gi = g[h]        + b_ih[h]        + b_hh[h];
    float gf = g[1024 + h] + b_ih[1024 + h] + b_hh[1024 + h];
    float gg = g[2048 + h] + b_ih[2048 + h] + b_hh[2048 + h];
    float go = g[3072 + h] + b_ih[3072 + h] + b_hh[3072 + h];
    float si = 1.f / (1.f + __expf(-gi));
    float sf = 1.f / (1.f + __expf(-gf));
    float so = 1.f / (1.f + __expf(-go));
    float cn = sf * c0[idx] + si * tanhf(gg);
    float hn = so * tanhf(cn);
    cout[idx] = cn;
    hout[idx] = hn;
}

// ---------------------------------------------------------------------------
extern "C" void kernel_launch(void* const* d_in, const int* in_sizes, int n_in,
                              void* d_out, int out_size, void* d_ws, size_t ws_size,
                              hipStream_t stream)
{
    const float* inp    = (const float*)d_in[0];
    const float* encv   = (const float*)d_in[1];
    const float* enca   = (const float*)d_in[2];
    const float* h0     = (const float*)d_in[3];
    const float* c0     = (const float*)d_in[4];
    const float* W_va1  = (const float*)d_in[5];
    const float* W_va2  = (const float*)d_in[6];
    const float* W_va3  = (const float*)d_in[7];
    const float* W_venc = (const float*)d_in[8];
    const float* W_aa1  = (const float*)d_in[9];
    const float* W_aa2  = (const float*)d_in[10];
    const float* W_aa3  = (const float*)d_in[11];
    const float* W_aenc = (const float*)d_in[12];
    const float* W_ca1  = (const float*)d_in[13];
    const float* W_ca2  = (const float*)d_in[14];
    const float* W_ca3  = (const float*)d_in[15];
    const float* W_ih   = (const float*)d_in[16];
    const float* W_hh   = (const float*)d_in[17];
    const float* b_ih   = (const float*)d_in[18];
    const float* b_hh   = (const float*)d_in[19];
    const float* W_out  = (const float*)d_in[20];
    const float* b_out  = (const float*)d_in[21];
    float* out = (float*)d_out;

    // workspace layout: [zero-initialized region | plain scratch]
    float* ws = (float*)d_ws;
    float* hv1  = ws;  ws += 128 * 512;                 // zeroed (atomic targets)
    float* ha1  = ws;  ws += 128 * 512;
    float* hc1  = ws;  ws += 128 * 512;
    float* scv  = ws;  ws += 128 * 64;
    float* sca  = ws;  ws += 128 * 128;
    float* ctx  = ws;  ws += 128 * 2 * 512;
    float* v2c  = ws;  ws += 128 * 2 * 512;
    float* gates= ws;  ws += (size_t)128 * 4096;
    size_t zero_floats = (size_t)(ws - (float*)d_ws);
    float* xb   = ws;  ws += 128 * 1024;
    float* attv = ws;  ws += 128 * 1024;
    float* atta = ws;  ws += 128 * 512;

    dim3 blk(256);

    // 0. zero all atomic-accumulation targets + the logits output region
    hipMemsetAsync(d_ws, 0, zero_floats * sizeof(float), stream);
    hipMemsetAsync(out, 0, (size_t)128 * 20000 * sizeof(float), stream);

    // 1. three h0 projections, one MFMA launch: grid (24, 8) = 192 blocks
    hproj3_mfma<<<dim3(24, 8), blk, 0, stream>>>(h0, W_va1, W_aa1, W_ca1, hv1);
    // 2. both encoder projections + fused tanh-scores: 1536 blocks, one launch
    scores_fused<<<dim3(1536), blk, 0, stream>>>(encv, W_va2, hv1, W_va3, scv,
                                                 enca, W_aa2, ha1, W_aa3, sca);
    // 3. softmax + weighted encoder sum, both modalities: grid (128, 6)
    attend_out2<<<dim3(128, 6), blk, 0, stream>>>(scv, encv, attv, sca, enca, atta);
    // 4. both context projections -> ctx[B,2,C]: grid (8,8,2) = 128 blocks
    ctxproj_mfma<<<dim3(8, 8, 2), blk, 0, stream>>>(attv, W_venc, atta, W_aenc, ctx);
    // 5. cross-modal key projection: split-K 4 -> 128 blocks
    gemm_sk<<<dim3(8, 4, 2), blk, 0, stream>>>(ctx, W_ca2, nullptr, v2c, 512, 512, 128, 512);
    // 6. cross-modal attention + x build
    cross_kernel<<<128, blk, 0, stream>>>(hc1, v2c, W_ca3, ctx, inp, xb);
    // 7. LSTM gates: both GEMMs, split-K 4 each: grid (64, 8) = 512 blocks
    gates_mfma<<<dim3(64, 8), blk, 0, stream>>>(xb, W_ih, h0, W_hh, gates);
    // 8. LSTM pointwise (+biases) -> h_new, c_new in d_out tail
    float* hout = out + 2560000;
    float* cout = out + 2560000 + 131072;
    lstm_kernel<<<512, blk, 0, stream>>>(gates, c0, b_ih, b_hh, hout, cout);
    // 9. logits: split-K 2, bias added by chunk 0. grid (313, 2) = 626 blocks
    gemm_sk<<<dim3(313, 2, 1), blk, 0, stream>>>(hout, W_out, b_out, out, 20000, 1024, 512, 20000);
}